// Round 8
// baseline (209.265 us; speedup 1.0000x reference)
//
#include <hip/hip_runtime.h>
#include <stdint.h>

// Shapes (fixed by the problem)
#define Bn 256
#define Un 128
#define Pn 64
#define Hn 768
#define Ototal 192   // 128 row-logit outputs + 64 col-logit outputs
#define KC 16        // split-K chunks in phase B (K=8192 -> 512 each)

#define LDB 72       // phaseB LDS row stride (ushorts): 144B = 9*16 (b128-aligned)

typedef short s4v __attribute__((ext_vector_type(4)));
typedef short s8v __attribute__((ext_vector_type(8)));
typedef float f4v __attribute__((ext_vector_type(4)));

__device__ __forceinline__ short f2bf(float x) {
  union { float f; uint32_t u; } c; c.f = x;
  uint32_t r = (c.u + 0x7fffu + ((c.u >> 16) & 1u)) >> 16;  // RNE
  return (short)(r & 0xffffu);
}

__device__ __forceinline__ float dot4(float4 v) {
  return v.x * v.x + v.y * v.y + v.z * v.z + v.w * v.w;
}

__device__ __forceinline__ s8v pack8(float4 x, float4 y) {
  s8v r;
  r[0] = f2bf(x.x); r[1] = f2bf(x.y); r[2] = f2bf(x.z); r[3] = f2bf(x.w);
  r[4] = f2bf(y.x); r[5] = f2bf(y.y); r[6] = f2bf(y.z); r[7] = f2bf(y.w);
  return r;
}

// async global->LDS, 16B per lane. LDS dest is wave-uniform base + lane*16.
__device__ __forceinline__ void gl16(const float* g, float* l) {
  __builtin_amdgcn_global_load_lds(
      (const __attribute__((address_space(1))) uint32_t*)g,
      (__attribute__((address_space(3))) uint32_t*)l, 16, 0, 0);
}

// ---------------------------------------------------------------------------
// Fused kernel: phaseA (cosine-sim, blocks 0..511) + convW (blocks 512..2623).
//
// phaseA v8 — r7's machinery, 2x DRAM run length. r0/r2/r3/r7 all pin at
// 65-70us with every pipe idle: ~5000cy/chunk of vmcnt wait = queuing, i.e.
// the memory system serves the 128B-at-786KB-stride pattern at ~3TB/s no
// matter the pipelining. Only the PATTERN is left: chunk 32->64 floats, so
// each row's 256B is read by two back-to-back gl16 issues (~100cy apart,
// one page-activation window) instead of two 128B touches ~2.8us apart.
// Everything else identical to r7: register-free gl16 staging, counted
// vmcnt(4) across raw s_barriers, both-sides XOR swizzle, XCD pairing.
// ---------------------------------------------------------------------------
__global__ void __launch_bounds__(512, 4) phaseAW(const float* __restrict__ utt,
                                                  const float* __restrict__ ph,
                                                  ushort* __restrict__ Cbf,
                                                  const float* __restrict__ w_utt,
                                                  const float* __restrict__ w_ph,
                                                  ushort* __restrict__ Wbf) {
  __shared__ __align__(16) char smem[66048];
  const int bx = blockIdx.x;
  const int t = threadIdx.x;

  if (bx >= 512) {
    if (bx < 2560) {
      // w_utt convert: 2048 blocks x 512 thr x 1 elem -> W'[o][k]=w_utt[o,i,j]
      int idx = (bx - 512) * 512 + t;             // 0 .. 128*8192-1
      Wbf[idx] = (ushort)f2bf(w_utt[idx]);
      return;
    }
    // w_ph transpose: 64 blocks, W'[128+oc][i*64+j] = w_ph[oc,j,i]
    float* tile = (float*)smem;                   // [j][i] 64 x 129 (+1 pad)
    const int oc = bx - 2560;
    const float* src = w_ph + (size_t)oc * 8192;  // [j][i] = 64 x 128
#pragma unroll
    for (int itr = 0; itr < 4; ++itr) {
      int idx = itr * 2048 + t * 4;               // 4 consecutive i of one j
      int j = idx >> 7, i = idx & 127;
      float4 v = *(const float4*)(src + idx);     // coalesced 16B
      tile[j * 129 + i + 0] = v.x;
      tile[j * 129 + i + 1] = v.y;
      tile[j * 129 + i + 2] = v.z;
      tile[j * 129 + i + 3] = v.w;
    }
    __syncthreads();
    const size_t obase = (size_t)(128 + oc) * 8192;
#pragma unroll
    for (int itr = 0; itr < 4; ++itr) {
      int k = itr * 2048 + t * 4;                 // k = i*64 + j
      int i = k >> 6, j = k & 63;
      s4v o4 = { f2bf(tile[(j + 0) * 129 + i]),
                 f2bf(tile[(j + 1) * 129 + i]),
                 f2bf(tile[(j + 2) * 129 + i]),
                 f2bf(tile[(j + 3) * 129 + i]) };
      *(s4v*)&Wbf[obase + k] = o4;                // coalesced 8B
    }
    return;
  }

  // ---- phaseA path (blocks 0..511) ----
  // LDS: uf[2][4096] f32 (32KB) | pf[2][4096] f32 (32KB) | inu[64] | inp[64]
  float (*uf)[4096] = (float (*)[4096])smem;
  float (*pf)[4096] = (float (*)[4096])(smem + 32768);
  float* s_inu = (float*)(smem + 65536);
  float* s_inp = (float*)(smem + 65792);

  const int b    = (bx & 7) | ((bx >> 4) << 3);   // XCD pairing
  const int half = (bx >> 3) & 1;
  const int w = t >> 6, l = t & 63;

  // staging: thread t -> row r (8 thr/row), 16B group gsw of each 128B slice
  // (source pre-swizzled so LINEAR LDS dest t*16 holds logical group
  //  (t&7)^(r&7); swizzle permutes within a row only -> row sums exact).
  const int r   = t >> 3;                         // 0..63
  const int gsw = (t & 7) ^ (r & 7);              // swizzled group 0..7

  const size_t rstride = (size_t)Bn * Hn;
  const float* ubase = utt + (size_t)b * Hn + (size_t)(half * 64 + r) * rstride + gsw * 4;
  const float* pbase = ph  + (size_t)b * Hn + (size_t)r * rstride + gsw * 4;

  // MFMA fragment geometry (mapping identical to verified r0/r7)
  const int m  = l & 15;
  const int G0 = (l >> 4) * 2;                    // logical f4-group (of 8)
  const int G1 = G0 + 1;
  const int it = w & 3;                           // i-tile (16 rows)
  const int jp = w >> 2;                          // j-half (32 cols)
  const int Ra  = it * 16 + m;
  const int Rb0 = jp * 32 + m;
  const int Rb1 = Rb0 + 16;
  const int sa  = Ra  & 7;                        // row swizzle keys
  const int sb0 = Rb0 & 7;
  const int sb1 = Rb1 & 7;

  f4v zero4 = {0.f, 0.f, 0.f, 0.f};
  f4v acc0 = zero4, acc1 = zero4;
  float ssu = 0.f, ssp = 0.f;

  // chunk = 64 floats/row (256B run, two back-to-back 128B slices k=0,1).
#define ISSUE(cc, bf) do {                                                    \
    gl16(ubase + (cc) * 64,      uf[bf] + t * 4);                             \
    gl16(ubase + (cc) * 64 + 32, uf[bf] + 2048 + t * 4);                      \
    gl16(pbase + (cc) * 64,      pf[bf] + t * 4);                             \
    gl16(pbase + (cc) * 64 + 32, pf[bf] + 2048 + t * 4);                      \
  } while (0)

#define COMPUTE(bf) do {                                                      \
    _Pragma("unroll")                                                         \
    for (int ks = 0; ks < 2; ++ks) {                                          \
      const float* uB = uf[bf] + ks * 2048;                                   \
      const float* pC = pf[bf] + ks * 2048;                                   \
      float4 fa0  = *(const float4*)(uB + Ra  * 32 + ((G0 ^ sa)  << 2));      \
      float4 fa1  = *(const float4*)(uB + Ra  * 32 + ((G1 ^ sa)  << 2));      \
      float4 fb00 = *(const float4*)(pC + Rb0 * 32 + ((G0 ^ sb0) << 2));      \
      float4 fb01 = *(const float4*)(pC + Rb0 * 32 + ((G1 ^ sb0) << 2));      \
      float4 fb10 = *(const float4*)(pC + Rb1 * 32 + ((G0 ^ sb1) << 2));      \
      float4 fb11 = *(const float4*)(pC + Rb1 * 32 + ((G1 ^ sb1) << 2));      \
      s8v af  = pack8(fa0, fa1);                                              \
      s8v bf0 = pack8(fb00, fb01);                                            \
      s8v bf1 = pack8(fb10, fb11);                                            \
      acc0 = __builtin_amdgcn_mfma_f32_16x16x32_bf16(af, bf0, acc0, 0, 0, 0); \
      acc1 = __builtin_amdgcn_mfma_f32_16x16x32_bf16(af, bf1, acc1, 0, 0, 0); \
    }                                                                         \
    float4 su0 = *(const float4*)(uf[bf] + t * 4);                            \
    float4 su1 = *(const float4*)(uf[bf] + 2048 + t * 4);                     \
    float4 sp0 = *(const float4*)(pf[bf] + t * 4);                            \
    float4 sp1 = *(const float4*)(pf[bf] + 2048 + t * 4);                     \
    ssu += dot4(su0) + dot4(su1);                                             \
    ssp += dot4(sp0) + dot4(sp1);                                             \
  } while (0)

  ISSUE(0, 0);                       // prologue: chunk 0 in flight

#pragma unroll
  for (int c = 0; c < 12; ++c) {
    if (c < 11) {                    // chunk c+1 stays in flight ACROSS barrier
      ISSUE(c + 1, (c + 1) & 1);
      __builtin_amdgcn_sched_barrier(0);
      asm volatile("s_waitcnt vmcnt(4)" ::: "memory");  // chunk c landed
    } else {
      asm volatile("s_waitcnt vmcnt(0)" ::: "memory");
    }
    __builtin_amdgcn_s_barrier();
    __builtin_amdgcn_sched_barrier(0);
    COMPUTE(c & 1);
    asm volatile("s_waitcnt lgkmcnt(0)" ::: "memory");  // LDS reads done
    __builtin_amdgcn_s_barrier();    // safe to overwrite buf next iter
    __builtin_amdgcn_sched_barrier(0);
  }

#undef ISSUE
#undef COMPUTE

  // row sumsq reductions: 8 threads/row are adjacent lanes
  ssu += __shfl_xor(ssu, 4); ssu += __shfl_xor(ssu, 2); ssu += __shfl_xor(ssu, 1);
  ssp += __shfl_xor(ssp, 4); ssp += __shfl_xor(ssp, 2); ssp += __shfl_xor(ssp, 1);
  if ((t & 7) == 0) {
    s_inu[r] = 1.f / fmaxf(sqrtf(ssu), 1e-8f);
    s_inp[r] = 1.f / fmaxf(sqrtf(ssp), 1e-8f);
  }
  __syncthreads();

  // epilogue: scale, store bf16 C[b][half*64+i][j]
  // D layout (verified m89/m91): col = lane&15, row = (lane>>4)*4 + reg
  const int cl = l & 15;
  const int rq = (l >> 4) * 4;
#pragma unroll
  for (int jt = 0; jt < 2; ++jt) {
    int j = jp * 32 + jt * 16 + cl;
    float sj = s_inp[j];
    f4v a = (jt == 0) ? acc0 : acc1;
#pragma unroll
    for (int rr = 0; rr < 4; ++rr) {
      int il = it * 16 + rq + rr;     // local row 0..63
      float v = a[rr] * s_inu[il] * sj;
      Cbf[((size_t)b * Un + half * 64 + il) * Pn + j] = (ushort)f2bf(v);
    }
  }
}

// ---------------------------------------------------------------------------
// Kernel 3: logits GEMM, M=256, N=192, K=8192, split-K (KC=16).
// ---------------------------------------------------------------------------
__global__ void __launch_bounds__(256) phaseB(const ushort* __restrict__ Cbf,
                                              const ushort* __restrict__ Wbf,
                                              float* __restrict__ partial) {
  const int kc = blockIdx.x;
  const int mt = blockIdx.y;
  const int nt = blockIdx.z;
  const int t = threadIdx.x;
  const int w = t >> 6, l = t & 63;

  __shared__ short Ab[64 * LDB];
  __shared__ short Bb[64 * LDB];

  const int row = t >> 2;          // 0..63
  const int k16 = (t & 3) * 16;    // 16 elems per thread per stage-row

  f4v zero4 = {0.f, 0.f, 0.f, 0.f};
  f4v acc[4] = {zero4, zero4, zero4, zero4};

  const ushort* Ag = Cbf + (size_t)(mt * 64 + row) * 8192 + kc * 512 + k16;
  const ushort* Bg = Wbf + (size_t)(nt * 64 + row) * 8192 + kc * 512 + k16;
  const int m  = l & 15;
  const int ko = (l >> 4) * 8;

  for (int c = 0; c < 8; ++c) {
    s8v av0 = *(const s8v*)(Ag + c * 64);
    s8v av1 = *(const s8v*)(Ag + c * 64 + 8);
    s8v bv0 = *(const s8v*)(Bg + c * 64);
    s8v bv1 = *(const s8v*)(Bg + c * 64 + 8);
    __syncthreads();
    *(s8v*)&Ab[row * LDB + k16]     = av0;
    *(s8v*)&Ab[row * LDB + k16 + 8] = av1;
    *(s8v*)&Bb[row * LDB + k16]     = bv0;
    *(s8v*)&Bb[row * LDB + k16 + 8] = bv1;
    __syncthreads();
#pragma unroll
    for (int ks = 0; ks < 2; ++ks) {
      s8v af = *(const s8v*)&Ab[(16 * w + m) * LDB + ks * 32 + ko];
#pragma unroll
      for (int jt = 0; jt < 4; ++jt) {
        s8v bf = *(const s8v*)&Bb[(16 * jt + m) * LDB + ks * 32 + ko];
        acc[jt] = __builtin_amdgcn_mfma_f32_16x16x32_bf16(af, bf, acc[jt], 0, 0, 0);
      }
    }
  }

  const int rq = (l >> 4) * 4;
#pragma unroll
  for (int jt = 0; jt < 4; ++jt) {
    int og = nt * 64 + 16 * jt + (l & 15);
#pragma unroll
    for (int r = 0; r < 4; ++r) {
      int bg = mt * 64 + 16 * w + rq + r;
      partial[((size_t)kc * Bn + bg) * Ototal + og] = acc[jt][r];
    }
  }
}

// ---------------------------------------------------------------------------
// Kernel 4: reduce split-K partials + bias + dual-group softmax.
// ---------------------------------------------------------------------------
__global__ void __launch_bounds__(192) phaseC(const float* __restrict__ partial,
                                              const float* __restrict__ b_utt,
                                              const float* __restrict__ b_ph,
                                              float* __restrict__ out) {
  const int b = blockIdx.x;
  const int t = threadIdx.x;      // 0..191
  const int w = t >> 6, l = t & 63;

  float v = 0.f;
#pragma unroll
  for (int kc = 0; kc < KC; ++kc)
    v += partial[((size_t)kc * Bn + b) * Ototal + t];
  v += (t < Un) ? b_utt[t] : b_ph[t - Un];

  __shared__ float red[3];
  float mx = v;
  for (int o = 32; o >= 1; o >>= 1) mx = fmaxf(mx, __shfl_xor(mx, o));
  if (l == 0) red[w] = mx;
  __syncthreads();
  float gmax = (t < Un) ? fmaxf(red[0], red[1]) : red[2];
  float e = expf(v - gmax);
  float s = e;
  for (int o = 32; o >= 1; o >>= 1) s += __shfl_xor(s, o);
  __syncthreads();
  if (l == 0) red[w] = s;
  __syncthreads();
  float gs = (t < Un) ? (red[0] + red[1]) : red[2];
  float r = e / gs;
  if (t < Un) out[(size_t)b * Un + t] = r;
  else        out[(size_t)Bn * Un + (size_t)b * Pn + (t - Un)] = r;
}

// ---------------------------------------------------------------------------
extern "C" void kernel_launch(void* const* d_in, const int* in_sizes, int n_in,
                              void* d_out, int out_size, void* d_ws, size_t ws_size,
                              hipStream_t stream) {
  const float* utt   = (const float*)d_in[0];  // [128,256,768]
  const float* ph    = (const float*)d_in[1];  // [64,256,768]
  const float* w_utt = (const float*)d_in[2];  // [128,128,64]
  const float* b_utt = (const float*)d_in[3];  // [128]
  const float* w_ph  = (const float*)d_in[4];  // [64,64,128]
  const float* b_ph  = (const float*)d_in[5];  // [64]

  char* ws = (char*)d_ws;
  ushort* Cbf     = (ushort*)(ws);                 // 256*128*64*2  = 4 MiB
  ushort* Wbf     = (ushort*)(ws + 4194304);       // 192*8192*2   = 3 MiB
  float*  partial = (float*)(ws + 7340032);        // 16*256*192*4 = 3 MiB

  phaseAW<<<dim3(2624), dim3(512), 0, stream>>>(utt, ph, Cbf, w_utt, w_ph, Wbf);
  phaseB <<<dim3(KC, 4, 3), dim3(256), 0, stream>>>(Cbf, Wbf, partial);
  phaseC <<<dim3(Bn), dim3(192), 0, stream>>>(partial, b_utt, b_ph, (float*)d_out);
}